// Round 8
// baseline (136.635 us; speedup 1.0000x reference)
//
#include <hip/hip_runtime.h>
#include <hip/hip_bf16.h>

// Problem constants (B,S,H,Q,D,C) = (8,512,768,64,256,2)
#define B_ 8
#define S_ 512
#define H_ 768
#define Q_ 64
#define D_ 256
#define EPSF 1e-8f

// ws layout (floats)
#define WS_QBARP  0                           // [8][B][H] = 49152
#define WS_QAP    (8 * B_ * H_)               // [8][B][H] = 49152
#define WS_W      (16 * B_ * H_)              // [B*D] = 2048
#define WS_HIDDEN (16 * B_ * H_ + B_ * D_)    // [B*H] = 6144
#define WS_CNT    (WS_HIDDEN + B_ * H_)       // wcnt[8] ints, gcnt at +8

// ============================================================================
// K1: 64 blocks x 512 threads; block = (b, qg) owns 8 q-rows.
//   Wave wv norms its row; column pass writes qbar/qa partials. Blocks 0..12
//   also zero hidden + counters (6153 floats < 13*512).
// ============================================================================
__global__ __launch_bounds__(512) void k_qnorm(
        const float* __restrict__ feats,
        const int* __restrict__ aidx,
        float* __restrict__ ws) {
    float* qbar_part = ws + WS_QBARP;
    float* qa_part   = ws + WS_QAP;
    const int b = blockIdx.x >> 3, qg = blockIdx.x & 7;
    const int t = threadIdx.x, wv = t >> 6, lane = t & 63;
    if (blockIdx.x < 13) ws[WS_HIDDEN + blockIdx.x * 512 + t] = 0.f;
    __shared__ int   s_ai[8];
    __shared__ float s_inv[8], s_m[8];
    if (t < 8) s_ai[t] = aidx[b * Q_ + qg * 8 + t];
    __syncthreads();
    {
        int idx = s_ai[wv];
        const float4* row4 = (const float4*)(feats + (size_t)(b * S_ + idx) * H_);
        float4 v0 = row4[lane], v1 = row4[lane + 64], v2 = row4[lane + 128];
        float ss = v0.x*v0.x + v0.y*v0.y + v0.z*v0.z + v0.w*v0.w
                 + v1.x*v1.x + v1.y*v1.y + v1.z*v1.z + v1.w*v1.w
                 + v2.x*v2.x + v2.y*v2.y + v2.z*v2.z + v2.w*v2.w;
        for (int off = 32; off; off >>= 1) ss += __shfl_xor(ss, off, 64);
        if (lane == 0) {
            float inv = 1.f / fmaxf(sqrtf(ss), EPSF);
            s_inv[wv] = (idx > 0) ? inv : 0.f;
            s_m[wv]   = (idx > 0) ? 1.f : 0.f;
        }
    }
    __syncthreads();
    float pb0 = 0.f, pa0 = 0.f, pb1 = 0.f, pa1 = 0.f;
#pragma unroll
    for (int j = 0; j < 8; ++j) {
        const float* row = feats + (size_t)(b * S_ + s_ai[j]) * H_;
        float iv = s_inv[j], mv = s_m[j];
        float f0 = row[t];
        pb0 += f0 * iv; pa0 += f0 * mv;
        if (t < 256) {
            float f1 = row[512 + t];
            pb1 += f1 * iv; pa1 += f1 * mv;
        }
    }
    size_t base = (size_t)(qg * B_ + b) * H_;
    qbar_part[base + t] = pb0;
    qa_part[base + t]   = pa0;
    if (t < 256) {
        qbar_part[base + 512 + t] = pb1;
        qa_part[base + 512 + t]   = pa1;
    }
}

// ============================================================================
// K2: 608 blocks x 256 threads.
//  blocks 0..511  (producer): docw — w[b,d] via one row pass (dual dot),
//      atomic stores, then per-batch counter release.
//  blocks 512..607 (consumer, (b,hc)): qa chunk + TOP-half W1 GEMV (overlaps
//      with producers), acquire-spin on wcnt[b]==64, docsum chunk,
//      BOTTOM-half GEMV, then gcnt-elected relu+logits tail (proven pattern).
// ============================================================================
__global__ __launch_bounds__(256) void k_fused2(
        const float* __restrict__ feats,
        const int* __restrict__ aidx,
        const int* __restrict__ bidx,
        const float* __restrict__ W1,
        const float* __restrict__ b1,
        const float* __restrict__ W2,
        const float* __restrict__ b2,
        float* __restrict__ ws,
        float* __restrict__ out) {
    const float* qbar_part = ws + WS_QBARP;
    const float* qa_part   = ws + WS_QAP;
    float* w       = ws + WS_W;
    float* hidden  = ws + WS_HIDDEN;
    int*   wcnt    = (int*)(ws + WS_CNT);
    int*   gcnt    = wcnt + 8;
    const int bk = blockIdx.x;
    const int t = threadIdx.x, wv = t >> 6, lane = t & 63;

    if (bk < 512) {
        // ------------------ producer: doc weights ------------------
        const int gw = bk * 4 + wv;          // 0..2047
        const int b = gw >> 8, d = gw & 255;
        __shared__ __align__(16) float s_qbar[H_];
        __shared__ int cnt[4];
        __shared__ float s_alen;
#pragma unroll
        for (int c = 0; c < 3; ++c) {
            int col = c * 256 + t;
            float s = 0.f;
#pragma unroll
            for (int p = 0; p < 8; ++p)
                s += qbar_part[(size_t)(p * B_ + b) * H_ + col];
            s_qbar[col] = s;
        }
        unsigned long long mb = __ballot(bidx[b * D_ + wv * 64 + lane] > 0);
        if (lane == 0) cnt[wv] = __popcll(mb);
        if (wv == 0) {
            unsigned long long ma = __ballot(aidx[b * Q_ + lane] > 0);
            if (lane == 0) s_alen = (float)__popcll(ma);
        }
        __syncthreads();
        float blen = (float)(cnt[0] + cnt[1] + cnt[2] + cnt[3]);
        int idx = bidx[b * D_ + d];
        const float4* row4 = (const float4*)(feats + (size_t)(b * S_ + idx) * H_);
        const float4* q4 = (const float4*)s_qbar;
        float dqf = 0.f, dff = 0.f;
#pragma unroll
        for (int k = 0; k < 3; ++k) {
            float4 v = row4[lane + k * 64];
            float4 q = q4[lane + k * 64];
            dqf += v.x*q.x + v.y*q.y + v.z*q.z + v.w*q.w;
            dff += v.x*v.x + v.y*v.y + v.z*v.z + v.w*v.w;
        }
        for (int off = 32; off; off >>= 1) {
            dqf += __shfl_xor(dqf, off, 64);
            dff += __shfl_xor(dff, off, 64);
        }
        if (lane == 0) {
            float invd = 1.f / fmaxf(sqrtf(dff), EPSF);
            float scale = 1.f / (s_alen * blen);
            float wd = (idx > 0) ? dqf * invd * scale : 0.f;
            __hip_atomic_store(&w[b * D_ + d], wd,
                               __ATOMIC_RELAXED, __HIP_MEMORY_SCOPE_AGENT);
        }
        __threadfence();
        __syncthreads();
        if (t == 0) atomicAdd(&wcnt[b], 1);
    } else {
        // ------------------ consumer: (b, hc) ------------------
        const int g = bk - 512;              // 0..95
        const int b = g / 12, hc = g % 12;
        __shared__ float s_w[D_];
        __shared__ int   s_i[D_];
        __shared__ float s_k[128];           // [0:64]=qa chunk, [64:128]=qbd
        __shared__ float red[4][64];
        __shared__ float s_alen;
        __shared__ int   s_flag;
        s_i[t] = bidx[b * D_ + t];
        if (wv == 0) {
            unsigned long long ma = __ballot(aidx[b * Q_ + lane] > 0);
            if (lane == 0) s_alen = (float)__popcll(ma);
        }
        __syncthreads();
        if (t < 64) {
            float s = 0.f;
#pragma unroll
            for (int p = 0; p < 8; ++p)
                s += qa_part[(size_t)(p * B_ + b) * H_ + hc * 64 + t];
            s_k[t] = s / s_alen;
        }
        __syncthreads();
        // TOP-half GEMV (independent of w) — overlaps with producers
        {
            const float* Wtop = W1 + (size_t)(hc * 64) * H_;
            float h0 = 0.f, h1 = 0.f, h2 = 0.f;
#pragma unroll 4
            for (int i = 0; i < 64; ++i) {
                float ka = s_k[i];
                const float* r1 = Wtop + (size_t)i * H_;
                h0 += ka * r1[t];
                h1 += ka * r1[t + 256];
                h2 += ka * r1[t + 512];
            }
            atomicAdd(&hidden[b * H_ + t],       h0);
            atomicAdd(&hidden[b * H_ + t + 256], h1);
            atomicAdd(&hidden[b * H_ + t + 512], h2);
        }
        // acquire-spin until this batch's 64 producer blocks are done
        if (t == 0) {
            while (__hip_atomic_load(&wcnt[b], __ATOMIC_ACQUIRE,
                                     __HIP_MEMORY_SCOPE_AGENT) < 64) {
                __builtin_amdgcn_s_sleep(2);
            }
        }
        __syncthreads();
        s_w[t] = __hip_atomic_load(&w[b * D_ + t], __ATOMIC_RELAXED,
                                   __HIP_MEMORY_SCOPE_AGENT);
        __syncthreads();
        // docsum chunk
        {
            int hh = hc * 64 + lane;
            float acc = 0.f;
#pragma unroll 8
            for (int d = wv * 64; d < wv * 64 + 64; ++d)
                acc += s_w[d] * feats[(size_t)(b * S_ + s_i[d]) * H_ + hh];
            red[wv][lane] = acc;
        }
        __syncthreads();
        if (t < 64) s_k[64 + t] = red[0][t] + red[1][t] + red[2][t] + red[3][t];
        __syncthreads();
        // BOTTOM-half GEMV
        {
            const float* Wbot = W1 + (size_t)(H_ + hc * 64) * H_;
            float h0 = 0.f, h1 = 0.f, h2 = 0.f;
#pragma unroll 4
            for (int i = 0; i < 64; ++i) {
                float kb = s_k[64 + i];
                const float* r2 = Wbot + (size_t)i * H_;
                h0 += kb * r2[t];
                h1 += kb * r2[t + 256];
                h2 += kb * r2[t + 512];
            }
            atomicAdd(&hidden[b * H_ + t],       h0);
            atomicAdd(&hidden[b * H_ + t + 256], h1);
            atomicAdd(&hidden[b * H_ + t + 512], h2);
        }
        __threadfence();
        __syncthreads();
        if (t == 0) {
            int old = atomicAdd(gcnt, 1);
            s_flag = (old == 95);
        }
        __syncthreads();
        if (s_flag) {
            __threadfence();
            for (int bb = wv * 2; bb < wv * 2 + 2; ++bb) {
                float a0 = 0.f, a1 = 0.f;
#pragma unroll
                for (int k = 0; k < 12; ++k) {
                    int h = lane + k * 64;
                    float hv = __hip_atomic_load(&hidden[bb * H_ + h],
                                                 __ATOMIC_RELAXED,
                                                 __HIP_MEMORY_SCOPE_AGENT);
                    float v = fmaxf(hv + b1[h], 0.f);
                    a0 += v * W2[h * 2 + 0];
                    a1 += v * W2[h * 2 + 1];
                }
                for (int off = 32; off; off >>= 1) {
                    a0 += __shfl_xor(a0, off, 64);
                    a1 += __shfl_xor(a1, off, 64);
                }
                if (lane == 0) {
                    out[bb * 2 + 0] = a0 + b2[0];
                    out[bb * 2 + 1] = a1 + b2[1];
                }
            }
        }
    }
}

extern "C" void kernel_launch(void* const* d_in, const int* in_sizes, int n_in,
                              void* d_out, int out_size, void* d_ws, size_t ws_size,
                              hipStream_t stream) {
    const float* feats = (const float*)d_in[0];
    const int*   aidx  = (const int*)d_in[1];
    const int*   bidx  = (const int*)d_in[2];
    const float* W1    = (const float*)d_in[3];
    const float* b1    = (const float*)d_in[4];
    const float* W2    = (const float*)d_in[5];
    const float* b2    = (const float*)d_in[6];
    float* out = (float*)d_out;
    float* ws = (float*)d_ws;

    k_qnorm<<<64, 512, 0, stream>>>(feats, aidx, ws);
    k_fused2<<<608, 256, 0, stream>>>(feats, aidx, bidx, W1, b1, W2, b2, ws, out);
}

// Round 9
// 100.105 us; speedup vs baseline: 1.3649x; 1.3649x over previous
//
#include <hip/hip_runtime.h>
#include <hip/hip_bf16.h>

// Problem constants (B,S,H,Q,D,C) = (8,512,768,64,256,2)
#define B_ 8
#define S_ 512
#define H_ 768
#define Q_ 64
#define D_ 256
#define EPSF 1e-8f

// ws layout (floats)
#define WS_QBARP  0                       // [8][B][H] = 49152
#define WS_QAP    (8 * B_ * H_)           // [8][B][H] = 49152
#define WS_HIDDEN (16 * B_ * H_)          // [B*H] = 6144
#define WS_QBD    (WS_HIDDEN + B_ * H_)   // [B*H] = 6144
#define WS_CNT    (WS_QBD + B_ * H_)      // gcnt (1 int) + pad
// zero region: WS_HIDDEN .. WS_HIDDEN+12320  (25 blocks x 512 covers 12800)

// ============================================================================
// K1: 64 blocks x 512 threads; block = (b, qg) owns 8 q-rows.
//   Wave wv norms its row; column pass writes qbar/qa partials.
//   Blocks 0..24 zero hidden + qbd + gcnt.
// ============================================================================
__global__ __launch_bounds__(512) void k_qnorm(
        const float* __restrict__ feats,
        const int* __restrict__ aidx,
        float* __restrict__ ws) {
    float* qbar_part = ws + WS_QBARP;
    float* qa_part   = ws + WS_QAP;
    const int b = blockIdx.x >> 3, qg = blockIdx.x & 7;
    const int t = threadIdx.x, wv = t >> 6, lane = t & 63;
    if (blockIdx.x < 25) ws[WS_HIDDEN + blockIdx.x * 512 + t] = 0.f;
    __shared__ int   s_ai[8];
    __shared__ float s_inv[8], s_m[8];
    if (t < 8) s_ai[t] = aidx[b * Q_ + qg * 8 + t];
    __syncthreads();
    {
        int idx = s_ai[wv];
        const float4* row4 = (const float4*)(feats + (size_t)(b * S_ + idx) * H_);
        float4 v0 = row4[lane], v1 = row4[lane + 64], v2 = row4[lane + 128];
        float ss = v0.x*v0.x + v0.y*v0.y + v0.z*v0.z + v0.w*v0.w
                 + v1.x*v1.x + v1.y*v1.y + v1.z*v1.z + v1.w*v1.w
                 + v2.x*v2.x + v2.y*v2.y + v2.z*v2.z + v2.w*v2.w;
        for (int off = 32; off; off >>= 1) ss += __shfl_xor(ss, off, 64);
        if (lane == 0) {
            float inv = 1.f / fmaxf(sqrtf(ss), EPSF);
            s_inv[wv] = (idx > 0) ? inv : 0.f;
            s_m[wv]   = (idx > 0) ? 1.f : 0.f;
        }
    }
    __syncthreads();
    float pb0 = 0.f, pa0 = 0.f, pb1 = 0.f, pa1 = 0.f;
#pragma unroll
    for (int j = 0; j < 8; ++j) {
        const float* row = feats + (size_t)(b * S_ + s_ai[j]) * H_;
        float iv = s_inv[j], mv = s_m[j];
        float f0 = row[t];
        pb0 += f0 * iv; pa0 += f0 * mv;
        if (t < 256) {
            float f1 = row[512 + t];
            pb1 += f1 * iv; pa1 += f1 * mv;
        }
    }
    size_t base = (size_t)(qg * B_ + b) * H_;
    qbar_part[base + t] = pb0;
    qa_part[base + t]   = pa0;
    if (t < 256) {
        qbar_part[base + 512 + t] = pb1;
        qa_part[base + 512 + t]   = pa1;
    }
}

// ============================================================================
// K2: 224 blocks x 256 threads, two independent roles (no cross-block sync):
//  blocks 0..127 (producer, 16 docs each): read each doc row ONCE; dual dot
//      -> w (butterfly leaves sums in all lanes); accumulate w*row into
//      per-wave LDS qbd; one global atomicAdd pass -> qbd_g[b].
//  blocks 128..223 ((b,hc)): qa chunk + TOP-half W1 GEMV -> atomicAdd hidden.
// ============================================================================
__global__ __launch_bounds__(256) void k_docw_qbd(
        const float* __restrict__ feats,
        const int* __restrict__ aidx,
        const int* __restrict__ bidx,
        const float* __restrict__ W1,
        float* __restrict__ ws) {
    const float* qbar_part = ws + WS_QBARP;
    const float* qa_part   = ws + WS_QAP;
    float* hidden = ws + WS_HIDDEN;
    float* qbd_g  = ws + WS_QBD;
    const int bk = blockIdx.x;
    const int t = threadIdx.x, wv = t >> 6, lane = t & 63;

    if (bk < 128) {
        // ---------------- producer: 16 docs of batch b ----------------
        const int b = bk >> 4, blk16 = bk & 15;
        __shared__ __align__(16) float s_qbar[H_];
        __shared__ __align__(16) float s_qbd[4][H_];
        __shared__ int   s_bi[16];
        __shared__ int   cnt[4];
        __shared__ float s_alen;
        // sum 8 qbar parts -> s_qbar; zero per-wave qbd
#pragma unroll
        for (int c = 0; c < 3; ++c) {
            int col = c * 256 + t;
            float s = 0.f;
#pragma unroll
            for (int p = 0; p < 8; ++p)
                s += qbar_part[(size_t)(p * B_ + b) * H_ + col];
            s_qbar[col] = s;
            s_qbd[0][col] = 0.f; s_qbd[1][col] = 0.f;
            s_qbd[2][col] = 0.f; s_qbd[3][col] = 0.f;
        }
        if (t < 16) s_bi[t] = bidx[b * D_ + blk16 * 16 + t];
        unsigned long long mb = __ballot(bidx[b * D_ + wv * 64 + lane] > 0);
        if (lane == 0) cnt[wv] = __popcll(mb);
        if (wv == 0) {
            unsigned long long ma = __ballot(aidx[b * Q_ + lane] > 0);
            if (lane == 0) s_alen = (float)__popcll(ma);
        }
        __syncthreads();
        float scale = 1.f / (s_alen * (float)(cnt[0] + cnt[1] + cnt[2] + cnt[3]));
        const float4* q4 = (const float4*)s_qbar;
        float4 qb0 = q4[lane], qb1 = q4[lane + 64], qb2 = q4[lane + 128];
        float4* qbdw = (float4*)&s_qbd[wv][0];
#pragma unroll
        for (int j = 0; j < 4; ++j) {
            int idx = s_bi[wv * 4 + j];
            const float4* row4 = (const float4*)(feats + (size_t)(b * S_ + idx) * H_);
            float4 v0 = row4[lane], v1 = row4[lane + 64], v2 = row4[lane + 128];
            float dqf = v0.x*qb0.x + v0.y*qb0.y + v0.z*qb0.z + v0.w*qb0.w
                      + v1.x*qb1.x + v1.y*qb1.y + v1.z*qb1.z + v1.w*qb1.w
                      + v2.x*qb2.x + v2.y*qb2.y + v2.z*qb2.z + v2.w*qb2.w;
            float dff = v0.x*v0.x + v0.y*v0.y + v0.z*v0.z + v0.w*v0.w
                      + v1.x*v1.x + v1.y*v1.y + v1.z*v1.z + v1.w*v1.w
                      + v2.x*v2.x + v2.y*v2.y + v2.z*v2.z + v2.w*v2.w;
            for (int off = 32; off; off >>= 1) {       // all lanes get sums
                dqf += __shfl_xor(dqf, off, 64);
                dff += __shfl_xor(dff, off, 64);
            }
            float invd = 1.f / fmaxf(sqrtf(dff), EPSF);
            float wd = (idx > 0) ? dqf * invd * scale : 0.f;
            float4 a0 = qbdw[lane], a1 = qbdw[lane + 64], a2 = qbdw[lane + 128];
            a0.x += wd*v0.x; a0.y += wd*v0.y; a0.z += wd*v0.z; a0.w += wd*v0.w;
            a1.x += wd*v1.x; a1.y += wd*v1.y; a1.z += wd*v1.z; a1.w += wd*v1.w;
            a2.x += wd*v2.x; a2.y += wd*v2.y; a2.z += wd*v2.z; a2.w += wd*v2.w;
            qbdw[lane] = a0; qbdw[lane + 64] = a1; qbdw[lane + 128] = a2;
        }
        __syncthreads();
#pragma unroll
        for (int c = 0; c < 3; ++c) {
            int col = c * 256 + t;
            float s = s_qbd[0][col] + s_qbd[1][col] + s_qbd[2][col] + s_qbd[3][col];
            atomicAdd(&qbd_g[b * H_ + col], s);
        }
    } else {
        // ---------------- TOP-half W1 GEMV: (b, hc) ----------------
        const int g = bk - 128;              // 0..95
        const int b = g / 12, hc = g % 12;
        __shared__ float s_k[64];
        __shared__ float s_alen;
        if (wv == 0) {
            unsigned long long ma = __ballot(aidx[b * Q_ + lane] > 0);
            if (lane == 0) s_alen = (float)__popcll(ma);
        }
        __syncthreads();
        if (t < 64) {
            float s = 0.f;
#pragma unroll
            for (int p = 0; p < 8; ++p)
                s += qa_part[(size_t)(p * B_ + b) * H_ + hc * 64 + t];
            s_k[t] = s / s_alen;
        }
        __syncthreads();
        const float* Wtop = W1 + (size_t)(hc * 64) * H_;
        float h0 = 0.f, h1 = 0.f, h2 = 0.f;
#pragma unroll 4
        for (int i = 0; i < 64; ++i) {
            float ka = s_k[i];
            const float* r1 = Wtop + (size_t)i * H_;
            h0 += ka * r1[t];
            h1 += ka * r1[t + 256];
            h2 += ka * r1[t + 512];
        }
        atomicAdd(&hidden[b * H_ + t],       h0);
        atomicAdd(&hidden[b * H_ + t + 256], h1);
        atomicAdd(&hidden[b * H_ + t + 512], h2);
    }
}

// ============================================================================
// K3: 96 blocks x 256 threads — (b,hc): BOTTOM-half W1 GEMV from qbd_g chunk,
//     atomicAdd hidden; gcnt-elected relu+logits tail (proven pattern).
// ============================================================================
__global__ __launch_bounds__(256) void k_mlp_bot(
        const float* __restrict__ W1,
        const float* __restrict__ b1,
        const float* __restrict__ W2,
        const float* __restrict__ b2,
        float* __restrict__ ws,
        float* __restrict__ out) {
    float* hidden = ws + WS_HIDDEN;
    const float* qbd_g = ws + WS_QBD;
    int* gcnt = (int*)(ws + WS_CNT);
    const int b = blockIdx.x / 12, hc = blockIdx.x % 12;
    const int t = threadIdx.x, wv = t >> 6, lane = t & 63;
    __shared__ float s_k[64];
    __shared__ int s_flag;
    if (t < 64) s_k[t] = qbd_g[b * H_ + hc * 64 + t];
    __syncthreads();
    const float* Wbot = W1 + (size_t)(H_ + hc * 64) * H_;
    float h0 = 0.f, h1 = 0.f, h2 = 0.f;
#pragma unroll 4
    for (int i = 0; i < 64; ++i) {
        float kb = s_k[i];
        const float* r2 = Wbot + (size_t)i * H_;
        h0 += kb * r2[t];
        h1 += kb * r2[t + 256];
        h2 += kb * r2[t + 512];
    }
    atomicAdd(&hidden[b * H_ + t],       h0);
    atomicAdd(&hidden[b * H_ + t + 256], h1);
    atomicAdd(&hidden[b * H_ + t + 512], h2);
    __threadfence();
    __syncthreads();
    if (t == 0) {
        int old = atomicAdd(gcnt, 1);
        s_flag = (old == 95);
    }
    __syncthreads();
    if (s_flag) {
        __threadfence();
        for (int bb = wv * 2; bb < wv * 2 + 2; ++bb) {
            float a0 = 0.f, a1 = 0.f;
#pragma unroll
            for (int k = 0; k < 12; ++k) {
                int h = lane + k * 64;
                float hv = __hip_atomic_load(&hidden[bb * H_ + h],
                                             __ATOMIC_RELAXED,
                                             __HIP_MEMORY_SCOPE_AGENT);
                float v = fmaxf(hv + b1[h], 0.f);
                a0 += v * W2[h * 2 + 0];
                a1 += v * W2[h * 2 + 1];
            }
            for (int off = 32; off; off >>= 1) {
                a0 += __shfl_xor(a0, off, 64);
                a1 += __shfl_xor(a1, off, 64);
            }
            if (lane == 0) {
                out[bb * 2 + 0] = a0 + b2[0];
                out[bb * 2 + 1] = a1 + b2[1];
            }
        }
    }
}

extern "C" void kernel_launch(void* const* d_in, const int* in_sizes, int n_in,
                              void* d_out, int out_size, void* d_ws, size_t ws_size,
                              hipStream_t stream) {
    const float* feats = (const float*)d_in[0];
    const int*   aidx  = (const int*)d_in[1];
    const int*   bidx  = (const int*)d_in[2];
    const float* W1    = (const float*)d_in[3];
    const float* b1    = (const float*)d_in[4];
    const float* W2    = (const float*)d_in[5];
    const float* b2    = (const float*)d_in[6];
    float* out = (float*)d_out;
    float* ws = (float*)d_ws;

    k_qnorm<<<64, 512, 0, stream>>>(feats, aidx, ws);
    k_docw_qbd<<<224, 256, 0, stream>>>(feats, aidx, bidx, W1, ws);
    k_mlp_bot<<<96, 256, 0, stream>>>(W1, b1, W2, b2, ws, out);
}

// Round 10
// 98.996 us; speedup vs baseline: 1.3802x; 1.0112x over previous
//
#include <hip/hip_runtime.h>
#include <hip/hip_bf16.h>

// Problem constants (B,S,H,Q,D,C) = (8,512,768,64,256,2)
#define B_ 8
#define S_ 512
#define H_ 768
#define Q_ 64
#define D_ 256
#define EPSF 1e-8f

// ws layout (floats)
#define WS_QBARP  0                       // [8][B][H] = 49152
#define WS_QAP    (8 * B_ * H_)           // [8][B][H] = 49152
#define WS_HIDDEN (16 * B_ * H_)          // [B*H] = 6144
#define WS_QBD    (WS_HIDDEN + B_ * H_)   // [B*H] = 6144
#define WS_CNT    (WS_QBD + B_ * H_)      // gcnt (1 int) + pad
// zero region: WS_HIDDEN .. +12800 (25 blocks x 512)

// ============================================================================
// K1: 64 blocks x 512 threads; block = (b, qg) owns 8 q-rows.
//   Wave wv norms its row; column pass writes qbar/qa partials.
//   Blocks 0..24 zero hidden + qbd + gcnt.
// ============================================================================
__global__ __launch_bounds__(512) void k_qnorm(
        const float* __restrict__ feats,
        const int* __restrict__ aidx,
        float* __restrict__ ws) {
    float* qbar_part = ws + WS_QBARP;
    float* qa_part   = ws + WS_QAP;
    const int b = blockIdx.x >> 3, qg = blockIdx.x & 7;
    const int t = threadIdx.x, wv = t >> 6, lane = t & 63;
    if (blockIdx.x < 25) ws[WS_HIDDEN + blockIdx.x * 512 + t] = 0.f;
    __shared__ int   s_ai[8];
    __shared__ float s_inv[8], s_m[8];
    if (t < 8) s_ai[t] = aidx[b * Q_ + qg * 8 + t];
    __syncthreads();
    {
        int idx = s_ai[wv];
        const float4* row4 = (const float4*)(feats + (size_t)(b * S_ + idx) * H_);
        float4 v0 = row4[lane], v1 = row4[lane + 64], v2 = row4[lane + 128];
        float ss = v0.x*v0.x + v0.y*v0.y + v0.z*v0.z + v0.w*v0.w
                 + v1.x*v1.x + v1.y*v1.y + v1.z*v1.z + v1.w*v1.w
                 + v2.x*v2.x + v2.y*v2.y + v2.z*v2.z + v2.w*v2.w;
        for (int off = 32; off; off >>= 1) ss += __shfl_xor(ss, off, 64);
        if (lane == 0) {
            float inv = 1.f / fmaxf(sqrtf(ss), EPSF);
            s_inv[wv] = (idx > 0) ? inv : 0.f;
            s_m[wv]   = (idx > 0) ? 1.f : 0.f;
        }
    }
    __syncthreads();
    float pb0 = 0.f, pa0 = 0.f, pb1 = 0.f, pa1 = 0.f;
#pragma unroll
    for (int j = 0; j < 8; ++j) {
        const float* row = feats + (size_t)(b * S_ + s_ai[j]) * H_;
        float iv = s_inv[j], mv = s_m[j];
        float f0 = row[t];
        pb0 += f0 * iv; pa0 += f0 * mv;
        if (t < 256) {
            float f1 = row[512 + t];
            pb1 += f1 * iv; pa1 += f1 * mv;
        }
    }
    size_t base = (size_t)(qg * B_ + b) * H_;
    qbar_part[base + t] = pb0;
    qa_part[base + t]   = pa0;
    if (t < 256) {
        qbar_part[base + 512 + t] = pb1;
        qa_part[base + 512 + t]   = pa1;
    }
}

// ============================================================================
// K2: 352 blocks x 256 threads, two independent roles (no cross-block sync):
//  blocks 0..255 (producer, 8 docs each, 2/wave): read each doc row ONCE;
//      dual dot -> w (butterfly leaves sums in all lanes); accumulate w*row
//      into per-wave LDS qbd; one global atomicAdd pass -> qbd_g[b].
//  blocks 256..351 ((b,hc)): qa chunk + TOP-half W1 GEMV -> atomicAdd hidden.
// ============================================================================
__global__ __launch_bounds__(256) void k_docw_qbd(
        const float* __restrict__ feats,
        const int* __restrict__ aidx,
        const int* __restrict__ bidx,
        const float* __restrict__ W1,
        float* __restrict__ ws) {
    const float* qbar_part = ws + WS_QBARP;
    const float* qa_part   = ws + WS_QAP;
    float* hidden = ws + WS_HIDDEN;
    float* qbd_g  = ws + WS_QBD;
    const int bk = blockIdx.x;
    const int t = threadIdx.x, wv = t >> 6, lane = t & 63;

    if (bk < 256) {
        // ---------------- producer: 8 docs of batch b ----------------
        const int b = bk >> 5, blk8 = bk & 31;
        __shared__ __align__(16) float s_qbar[H_];
        __shared__ __align__(16) float s_qbd[4][H_];
        __shared__ int   s_bi[8];
        __shared__ int   cnt[4];
        __shared__ float s_alen;
#pragma unroll
        for (int c = 0; c < 3; ++c) {
            int col = c * 256 + t;
            float s = 0.f;
#pragma unroll
            for (int p = 0; p < 8; ++p)
                s += qbar_part[(size_t)(p * B_ + b) * H_ + col];
            s_qbar[col] = s;
            s_qbd[0][col] = 0.f; s_qbd[1][col] = 0.f;
            s_qbd[2][col] = 0.f; s_qbd[3][col] = 0.f;
        }
        if (t < 8) s_bi[t] = bidx[b * D_ + blk8 * 8 + t];
        unsigned long long mb = __ballot(bidx[b * D_ + wv * 64 + lane] > 0);
        if (lane == 0) cnt[wv] = __popcll(mb);
        if (wv == 0) {
            unsigned long long ma = __ballot(aidx[b * Q_ + lane] > 0);
            if (lane == 0) s_alen = (float)__popcll(ma);
        }
        __syncthreads();
        float scale = 1.f / (s_alen * (float)(cnt[0] + cnt[1] + cnt[2] + cnt[3]));
        const float4* q4 = (const float4*)s_qbar;
        float4 qb0 = q4[lane], qb1 = q4[lane + 64], qb2 = q4[lane + 128];
        float4* qbdw = (float4*)&s_qbd[wv][0];
#pragma unroll
        for (int j = 0; j < 2; ++j) {
            int idx = s_bi[wv * 2 + j];
            const float4* row4 = (const float4*)(feats + (size_t)(b * S_ + idx) * H_);
            float4 v0 = row4[lane], v1 = row4[lane + 64], v2 = row4[lane + 128];
            float dqf = v0.x*qb0.x + v0.y*qb0.y + v0.z*qb0.z + v0.w*qb0.w
                      + v1.x*qb1.x + v1.y*qb1.y + v1.z*qb1.z + v1.w*qb1.w
                      + v2.x*qb2.x + v2.y*qb2.y + v2.z*qb2.z + v2.w*qb2.w;
            float dff = v0.x*v0.x + v0.y*v0.y + v0.z*v0.z + v0.w*v0.w
                      + v1.x*v1.x + v1.y*v1.y + v1.z*v1.z + v1.w*v1.w
                      + v2.x*v2.x + v2.y*v2.y + v2.z*v2.z + v2.w*v2.w;
            for (int off = 32; off; off >>= 1) {       // all lanes get sums
                dqf += __shfl_xor(dqf, off, 64);
                dff += __shfl_xor(dff, off, 64);
            }
            float invd = 1.f / fmaxf(sqrtf(dff), EPSF);
            float wd = (idx > 0) ? dqf * invd * scale : 0.f;
            float4 a0 = qbdw[lane], a1 = qbdw[lane + 64], a2 = qbdw[lane + 128];
            a0.x += wd*v0.x; a0.y += wd*v0.y; a0.z += wd*v0.z; a0.w += wd*v0.w;
            a1.x += wd*v1.x; a1.y += wd*v1.y; a1.z += wd*v1.z; a1.w += wd*v1.w;
            a2.x += wd*v2.x; a2.y += wd*v2.y; a2.z += wd*v2.z; a2.w += wd*v2.w;
            qbdw[lane] = a0; qbdw[lane + 64] = a1; qbdw[lane + 128] = a2;
        }
        __syncthreads();
#pragma unroll
        for (int c = 0; c < 3; ++c) {
            int col = c * 256 + t;
            float s = s_qbd[0][col] + s_qbd[1][col] + s_qbd[2][col] + s_qbd[3][col];
            atomicAdd(&qbd_g[b * H_ + col], s);
        }
    } else {
        // ---------------- TOP-half W1 GEMV: (b, hc) ----------------
        const int g = bk - 256;              // 0..95
        const int b = g / 12, hc = g % 12;
        __shared__ float s_k[64];
        __shared__ float s_alen;
        if (wv == 0) {
            unsigned long long ma = __ballot(aidx[b * Q_ + lane] > 0);
            if (lane == 0) s_alen = (float)__popcll(ma);
        }
        __syncthreads();
        if (t < 64) {
            float s = 0.f;
#pragma unroll
            for (int p = 0; p < 8; ++p)
                s += qa_part[(size_t)(p * B_ + b) * H_ + hc * 64 + t];
            s_k[t] = s / s_alen;
        }
        __syncthreads();
        const float* Wtop = W1 + (size_t)(hc * 64) * H_;
        float h0 = 0.f, h1 = 0.f, h2 = 0.f;
#pragma unroll 4
        for (int i = 0; i < 64; ++i) {
            float ka = s_k[i];
            const float* r1 = Wtop + (size_t)i * H_;
            h0 += ka * r1[t];
            h1 += ka * r1[t + 256];
            h2 += ka * r1[t + 512];
        }
        atomicAdd(&hidden[b * H_ + t],       h0);
        atomicAdd(&hidden[b * H_ + t + 256], h1);
        atomicAdd(&hidden[b * H_ + t + 512], h2);
    }
}

// ============================================================================
// K3: 96 blocks x 256 threads — (b,hc): BOTTOM-half W1 GEMV from qbd_g chunk,
//     atomicAdd hidden; gcnt-elected relu+logits tail (proven pattern).
// ============================================================================
__global__ __launch_bounds__(256) void k_mlp_bot(
        const float* __restrict__ W1,
        const float* __restrict__ b1,
        const float* __restrict__ W2,
        const float* __restrict__ b2,
        float* __restrict__ ws,
        float* __restrict__ out) {
    float* hidden = ws + WS_HIDDEN;
    const float* qbd_g = ws + WS_QBD;
    int* gcnt = (int*)(ws + WS_CNT);
    const int b = blockIdx.x / 12, hc = blockIdx.x % 12;
    const int t = threadIdx.x, wv = t >> 6, lane = t & 63;
    __shared__ float s_k[64];
    __shared__ int s_flag;
    if (t < 64) s_k[t] = qbd_g[b * H_ + hc * 64 + t];
    __syncthreads();
    const float* Wbot = W1 + (size_t)(H_ + hc * 64) * H_;
    float h0 = 0.f, h1 = 0.f, h2 = 0.f;
#pragma unroll 4
    for (int i = 0; i < 64; ++i) {
        float kb = s_k[i];
        const float* r2 = Wbot + (size_t)i * H_;
        h0 += kb * r2[t];
        h1 += kb * r2[t + 256];
        h2 += kb * r2[t + 512];
    }
    atomicAdd(&hidden[b * H_ + t],       h0);
    atomicAdd(&hidden[b * H_ + t + 256], h1);
    atomicAdd(&hidden[b * H_ + t + 512], h2);
    __threadfence();
    __syncthreads();
    if (t == 0) {
        int old = atomicAdd(gcnt, 1);
        s_flag = (old == 95);
    }
    __syncthreads();
    if (s_flag) {
        __threadfence();
        for (int bb = wv * 2; bb < wv * 2 + 2; ++bb) {
            float a0 = 0.f, a1 = 0.f;
#pragma unroll
            for (int k = 0; k < 12; ++k) {
                int h = lane + k * 64;
                float hv = __hip_atomic_load(&hidden[bb * H_ + h],
                                             __ATOMIC_RELAXED,
                                             __HIP_MEMORY_SCOPE_AGENT);
                float v = fmaxf(hv + b1[h], 0.f);
                a0 += v * W2[h * 2 + 0];
                a1 += v * W2[h * 2 + 1];
            }
            for (int off = 32; off; off >>= 1) {
                a0 += __shfl_xor(a0, off, 64);
                a1 += __shfl_xor(a1, off, 64);
            }
            if (lane == 0) {
                out[bb * 2 + 0] = a0 + b2[0];
                out[bb * 2 + 1] = a1 + b2[1];
            }
        }
    }
}

extern "C" void kernel_launch(void* const* d_in, const int* in_sizes, int n_in,
                              void* d_out, int out_size, void* d_ws, size_t ws_size,
                              hipStream_t stream) {
    const float* feats = (const float*)d_in[0];
    const int*   aidx  = (const int*)d_in[1];
    const int*   bidx  = (const int*)d_in[2];
    const float* W1    = (const float*)d_in[3];
    const float* b1    = (const float*)d_in[4];
    const float* W2    = (const float*)d_in[5];
    const float* b2    = (const float*)d_in[6];
    float* out = (float*)d_out;
    float* ws = (float*)d_ws;

    k_qnorm<<<64, 512, 0, stream>>>(feats, aidx, ws);
    k_docw_qbd<<<352, 256, 0, stream>>>(feats, aidx, bidx, W1, ws);
    k_mlp_bot<<<96, 256, 0, stream>>>(W1, b1, W2, b2, ws, out);
}